// Round 2
// baseline (233.030 us; speedup 1.0000x reference)
//
#include <hip/hip_runtime.h>
#include <hip/hip_bf16.h>

#define S_LEN 4096
#define E_DIM 512
#define B_DIM 2
#define M_ROWS (B_DIM * S_LEN)   // 8192

typedef __attribute__((ext_vector_type(8))) short short8;   // 8 bf16 = 4 VGPRs
typedef __attribute__((ext_vector_type(4))) float floatx4;  // MFMA C/D

__device__ __forceinline__ unsigned short f2bf(float f) {
    unsigned u = __float_as_uint(f);
    unsigned r = (u + 0x7fffu + ((u >> 16) & 1u)) >> 16;   // RNE
    return (unsigned short)r;
}
__device__ __forceinline__ float bf2f(unsigned short u) {
    return __uint_as_float((unsigned)u << 16);
}

// async 16B/lane global->LDS (lds dest = wave-uniform base + lane*16)
__device__ __forceinline__ void async_copy16(unsigned short* lds, const unsigned short* g) {
    auto gp = (const __attribute__((address_space(1))) unsigned int*)g;
    auto lp = (__attribute__((address_space(3))) unsigned int*)lds;
    __builtin_amdgcn_global_load_lds(gp, lp, 16, 0, 0);
}

// 576 live (tile,ch,bb) blocks; enc = t | ch<<6 | bb<<9
struct MapArg { unsigned short m[576]; };

// ---------------- convert fp32 inputs -> bf16 workspace ----------------
// dstU gets [x | Wq | Wk | Wv] (region later reused for Oh); Wo goes to dstWo.
__global__ __launch_bounds__(256) void convert_bf16(
    const float* __restrict__ x,  const float* __restrict__ wq,
    const float* __restrict__ wk, const float* __restrict__ wv,
    const float* __restrict__ wo, unsigned short* __restrict__ dstU,
    unsigned short* __restrict__ dstWo)
{
    long i = (long)blockIdx.x * 1024 + (long)threadIdx.x * 4;
    const float* src; long off; unsigned short* dst; long doff;
    if      (i < 4194304) { src = x;  off = i;           dst = dstU;  doff = i; }
    else if (i < 4456448) { src = wq; off = i - 4194304; dst = dstU;  doff = i; }
    else if (i < 4718592) { src = wk; off = i - 4456448; dst = dstU;  doff = i; }
    else if (i < 4980736) { src = wv; off = i - 4718592; dst = dstU;  doff = i; }
    else                  { src = wo; off = i - 4980736; dst = dstWo; doff = i - 4980736; }
    float4 v = *(const float4*)(src + off);
    ushort4 o;
    o.x = f2bf(v.x); o.y = f2bf(v.y); o.z = f2bf(v.z); o.w = f2bf(v.w);
    *(ushort4*)(dst + doff) = o;
}

// ---------------- MFMA GEMM core: C[m,n] = sum_k A[m,k]*W[n,k] ----------------
__device__ __forceinline__ void gemm_core(
    const unsigned short* __restrict__ A, const unsigned short* __restrict__ W,
    void* __restrict__ Cv, const float* __restrict__ bias, int mode,
    int m0, int n0)
{
    __shared__ unsigned short As[128 * 32];
    __shared__ unsigned short Bs[128 * 32];
    const int tid = threadIdx.x;
    const int lane = tid & 63, wave = tid >> 6;
    const int wm = wave >> 1, wn = wave & 1;
    const int q4 = lane >> 4, l16 = lane & 15;

    floatx4 acc[4][4];
#pragma unroll
    for (int i = 0; i < 4; ++i)
#pragma unroll
        for (int j = 0; j < 4; ++j) acc[i][j] = (floatx4){0.f, 0.f, 0.f, 0.f};

    const int srow = lane >> 2;
    const int scol = (lane & 3) * 8;

    for (int k0 = 0; k0 < 512; k0 += 32) {
        async_copy16(&As[(wave * 16) * 32],
                     A + (size_t)(m0 + wave * 16 + srow) * 512 + k0 + scol);
        async_copy16(&As[(64 + wave * 16) * 32],
                     A + (size_t)(m0 + 64 + wave * 16 + srow) * 512 + k0 + scol);
        async_copy16(&Bs[(wave * 16) * 32],
                     W + (size_t)(n0 + wave * 16 + srow) * 512 + k0 + scol);
        async_copy16(&Bs[(64 + wave * 16) * 32],
                     W + (size_t)(n0 + 64 + wave * 16 + srow) * 512 + k0 + scol);
        __syncthreads();
        short8 af[4], bfr[4];
#pragma unroll
        for (int i = 0; i < 4; ++i) {
            af[i]  = *(const short8*)&As[(wm * 64 + i * 16 + l16) * 32 + q4 * 8];
            bfr[i] = *(const short8*)&Bs[(wn * 64 + i * 16 + l16) * 32 + q4 * 8];
        }
#pragma unroll
        for (int i = 0; i < 4; ++i)
#pragma unroll
            for (int j = 0; j < 4; ++j)
                acc[i][j] = __builtin_amdgcn_mfma_f32_16x16x32_bf16(af[i], bfr[j], acc[i][j], 0, 0, 0);
        __syncthreads();
    }

    if (mode == 0) {
        unsigned short* C = (unsigned short*)Cv;
#pragma unroll
        for (int i = 0; i < 4; ++i) {
            int rowb = m0 + wm * 64 + i * 16 + q4 * 4;
#pragma unroll
            for (int j = 0; j < 4; ++j) {
                int col = n0 + wn * 64 + j * 16 + l16;
#pragma unroll
                for (int rg = 0; rg < 4; ++rg)
                    C[(size_t)(rowb + rg) * 512 + col] = f2bf(acc[i][j][rg]);
            }
        }
    } else if (mode == 1) {
        unsigned short* C = (unsigned short*)Cv;
#pragma unroll
        for (int i = 0; i < 4; ++i) {
            int grow = m0 + wm * 64 + i * 16 + q4 * 4;
            int b = grow >> 12, s = grow & 4095;
#pragma unroll
            for (int j = 0; j < 4; ++j) {
                int e = n0 + wn * 64 + j * 16 + l16;
                ushort4 pk;
                pk.x = f2bf(acc[i][j][0]); pk.y = f2bf(acc[i][j][1]);
                pk.z = f2bf(acc[i][j][2]); pk.w = f2bf(acc[i][j][3]);
                *(ushort4*)(C + (size_t)b * 512 * 4096 + (size_t)e * 4096 + s) = pk;
            }
        }
    } else {
        float* C = (float*)Cv;
#pragma unroll
        for (int i = 0; i < 4; ++i) {
            int rowb = m0 + wm * 64 + i * 16 + q4 * 4;
#pragma unroll
            for (int j = 0; j < 4; ++j) {
                int col = n0 + wn * 64 + j * 16 + l16;
                float bv = bias[col];
#pragma unroll
                for (int rg = 0; rg < 4; ++rg)
                    C[(size_t)(rowb + rg) * 512 + col] = acc[i][j][rg] + bv;
            }
        }
    }
}

__global__ __launch_bounds__(256) void gemm_qkv(
    const unsigned short* __restrict__ xb,
    const unsigned short* __restrict__ Wqb, const unsigned short* __restrict__ Wkb,
    const unsigned short* __restrict__ Wvb,
    unsigned short* __restrict__ Qb, unsigned short* __restrict__ Kb,
    unsigned short* __restrict__ Vtb)
{
    const int z = blockIdx.z;
    const unsigned short* W = (z == 0) ? Wqb : (z == 1) ? Wkb : Wvb;
    unsigned short* C = (z == 0) ? Qb : (z == 1) ? Kb : Vtb;
    gemm_core(xb, W, C, nullptr, (z == 2) ? 1 : 0, blockIdx.y * 128, blockIdx.x * 128);
}

__global__ __launch_bounds__(256) void gemm_out(
    const unsigned short* __restrict__ AOb, const unsigned short* __restrict__ Wob,
    const float* __restrict__ bo, float* __restrict__ out)
{
    gemm_core(AOb, Wob, out, bo, 2, blockIdx.y * 128, blockIdx.x * 128);
}

// ---------------- MFMA flash attention, Tm=64, Tn=32, 512 thr ----------------
// Anti-causal (keep j >= i). 8 key-chunks of 512 -> 576 blocks so every CU gets
// 2 concurrently-resident blocks (VGPR 116 -> 4 waves/SIMD -> 2 blk/CU); map is
// built host-side as balanced triples/pairs (sum 34/32 steps per CU).
__global__ __launch_bounds__(512, 2) void flash_mfma(
    const unsigned short* __restrict__ Qg, const unsigned short* __restrict__ Kg,
    const unsigned short* __restrict__ Vt,
    unsigned short* __restrict__ Oh, float* __restrict__ Lb, MapArg map)
{
    const int enc = map.m[blockIdx.x];
    const int tile = enc & 63, ch = (enc >> 6) & 7, bb = enc >> 9;
    const int i0 = tile * 64;
    const int lo0 = 512 * ch, hi = lo0 + 512;
    const int lo = (i0 > lo0) ? i0 : lo0;

    const int tid = threadIdx.x;
    const int lane = tid & 63, w = tid >> 6;
    const int s = w & 3, h = w >> 2;          // dim-slice, key-half
    const int q4 = lane >> 4, l16 = lane & 15;
    const float scale = 0.044194173824159216f;  // 1/sqrt(512)
    const float MREF = 4.0f;

    __shared__ float Sred[4][64][36];         // [slice][row][key 32+4pad] 36.9 KB
    __shared__ unsigned short Plds[64][40];   // [row][key] bf16
    __shared__ float Lred[64][8];

    const size_t rowbase = (size_t)bb * S_LEN;
    const size_t vbase   = (size_t)bb * 512 * 4096;

    // Q B-frags: all 64 rows, dims [128s, 128s+128)  (resident)
    short8 aq[4][4];
#pragma unroll
    for (int mg = 0; mg < 4; ++mg)
#pragma unroll
        for (int ks = 0; ks < 4; ++ks)
            aq[mg][ks] = *(const short8*)(Qg + (rowbase + i0 + mg * 16 + l16) * 512
                                          + s * 128 + ks * 32 + q4 * 8);

    floatx4 oacc[4][4];   // 64 rows x cols [64w, 64w+64)
#pragma unroll
    for (int mg = 0; mg < 4; ++mg)
#pragma unroll
        for (int nc = 0; nc < 4; ++nc) oacc[mg][nc] = (floatx4){0.f, 0.f, 0.f, 0.f};

    const int r = tid >> 3;   // softmax row 0..63
    const int g = tid & 7;    // key group (4 keys)
    float l_acc = 0.f;

    auto step = [&](int j0, short8 (&bkc)[4], short8 (&bkn)[4], int jn) {
        short8 vf[4];
#pragma unroll
        for (int nc = 0; nc < 4; ++nc)
            vf[nc] = *(const short8*)(Vt + vbase
                + (size_t)(w * 64 + nc * 16 + l16) * 4096 + j0 + q4 * 8);
#pragma unroll
        for (int ks = 0; ks < 4; ++ks)
            bkn[ks] = *(const short8*)(Kg + (rowbase + jn + h * 16 + l16) * 512
                                       + s * 128 + ks * 32 + q4 * 8);
        // S^T = K * Q^T partial: A=K-frag (m=16 keys), B=Q-frag (n=16 rows)
        floatx4 sf[4];
#pragma unroll
        for (int mg = 0; mg < 4; ++mg) sf[mg] = (floatx4){0.f, 0.f, 0.f, 0.f};
        __builtin_amdgcn_s_setprio(1);
#pragma unroll
        for (int ks = 0; ks < 4; ++ks)
#pragma unroll
            for (int mg = 0; mg < 4; ++mg)
                sf[mg] = __builtin_amdgcn_mfma_f32_16x16x32_bf16(
                    bkc[ks], aq[mg][ks], sf[mg], 0, 0, 0);
        __builtin_amdgcn_s_setprio(0);
        // lane (q4,l16): row = mg*16+l16, keys = h*16+q4*4+{0..3} -> b128 store
#pragma unroll
        for (int mg = 0; mg < 4; ++mg)
            *(floatx4*)&Sred[s][mg * 16 + l16][h * 16 + q4 * 4] = sf[mg];
        __syncthreads();

        // softmax (fixed ref): thread = (row r, keys j0+4g..+3)
        float4 a0 = *(const float4*)&Sred[0][r][4 * g];
        float4 a1 = *(const float4*)&Sred[1][r][4 * g];
        float4 a2 = *(const float4*)&Sred[2][r][4 * g];
        float4 a3 = *(const float4*)&Sred[3][r][4 * g];
        float sv[4] = { a0.x + a1.x + a2.x + a3.x, a0.y + a1.y + a2.y + a3.y,
                        a0.z + a1.z + a2.z + a3.z, a0.w + a1.w + a2.w + a3.w };
        ushort4 pk;
        float p0, p1, p2, p3;
        {
            int key = j0 + 4 * g;
            int row = i0 + r;
            p0 = (key + 0 >= row) ? __expf(sv[0] * scale - MREF) : 0.f;
            p1 = (key + 1 >= row) ? __expf(sv[1] * scale - MREF) : 0.f;
            p2 = (key + 2 >= row) ? __expf(sv[2] * scale - MREF) : 0.f;
            p3 = (key + 3 >= row) ? __expf(sv[3] * scale - MREF) : 0.f;
        }
        l_acc += p0 + p1 + p2 + p3;
        pk.x = f2bf(p0); pk.y = f2bf(p1); pk.z = f2bf(p2); pk.w = f2bf(p3);
        *(ushort4*)&Plds[r][4 * g] = pk;
        __syncthreads();

        // PV: O[rows][64w..64w+64) += P * V
        short8 ap[4];
#pragma unroll
        for (int mg = 0; mg < 4; ++mg)
            ap[mg] = *(const short8*)&Plds[mg * 16 + l16][q4 * 8];
        __builtin_amdgcn_s_setprio(1);
#pragma unroll
        for (int mg = 0; mg < 4; ++mg)
#pragma unroll
            for (int nc = 0; nc < 4; ++nc)
                oacc[mg][nc] = __builtin_amdgcn_mfma_f32_16x16x32_bf16(
                    ap[mg], vf[nc], oacc[mg][nc], 0, 0, 0);
        __builtin_amdgcn_s_setprio(0);
    };

    short8 bkA[4], bkB[4];
    int j0 = hi - 32;
#pragma unroll
    for (int ks = 0; ks < 4; ++ks)
        bkA[ks] = *(const short8*)(Kg + (rowbase + j0 + h * 16 + l16) * 512
                                   + s * 128 + ks * 32 + q4 * 8);
    while (j0 >= lo) {
        int jn = (j0 - 32 >= lo) ? j0 - 32 : lo;
        step(j0, bkA, bkB, jn);
        j0 -= 32;
        if (j0 < lo) break;
        jn = (j0 - 32 >= lo) ? j0 - 32 : lo;
        step(j0, bkB, bkA, jn);
        j0 -= 32;
    }
    __syncthreads();

    // packed slot for this (ch, bb, tile): slots 0..575
    const int slot = 8 * ch * (ch + 1) + bb * 8 * (ch + 1) + tile;

    Lred[r][g] = l_acc;
    __syncthreads();
    if (tid < 64) {
        float sum = 0.f;
#pragma unroll
        for (int gg = 0; gg < 8; ++gg) sum += Lred[tid][gg];
        Lb[(size_t)slot * 64 + tid] = sum;
    }

    unsigned short* Op = Oh + (size_t)slot * 64 * 512;
#pragma unroll
    for (int mg = 0; mg < 4; ++mg)
#pragma unroll
        for (int nc = 0; nc < 4; ++nc)
#pragma unroll
            for (int rg = 0; rg < 4; ++rg)
                Op[(size_t)(mg * 16 + q4 * 4 + rg) * 512 + w * 64 + nc * 16 + l16]
                    = f2bf(oacc[mg][nc][rg]);
}

// O = (sum_ch Ohat_ch) / (sum_ch l_ch) over valid chunks ch >= i>>9
__global__ __launch_bounds__(256) void flash_merge(
    const unsigned short* __restrict__ Oh, const float* __restrict__ Lb,
    unsigned short* __restrict__ AO)
{
    const int row = blockIdx.x;            // 0..8191
    const int c = threadIdx.x * 2;
    const int bb = row >> 12, i = row & 4095;
    const int t = i >> 6, ri = i & 63;
    const int chmin = i >> 9;
    float lsum = 0.f, v0 = 0.f, v1 = 0.f;
    for (int ch = chmin; ch < 8; ++ch) {
        int slot = 8 * ch * (ch + 1) + bb * 8 * (ch + 1) + t;
        lsum += Lb[(size_t)slot * 64 + ri];
        const unsigned short* p = Oh + (size_t)slot * 64 * 512 + (size_t)ri * 512 + c;
        v0 += bf2f(p[0]);
        v1 += bf2f(p[1]);
    }
    float inv = 1.f / lsum;
    ushort2 o; o.x = f2bf(v0 * inv); o.y = f2bf(v1 * inv);
    *(ushort2*)(AO + (size_t)row * 512 + c) = o;
}

static MapArg build_map() {
    // enumerate 576 live blocks with step counts
    int enc[576], steps[576], n = 0;
    for (int bb = 0; bb < 2; ++bb)
        for (int ch = 0; ch < 8; ++ch)
            for (int t = 0; t < 8 * (ch + 1); ++t) {
                int i0 = t * 64, lo0 = 512 * ch, hi = lo0 + 512;
                int lo = (i0 > lo0) ? i0 : lo0;
                enc[n] = t | (ch << 6) | (bb << 9);
                steps[n] = (hi - lo) / 32;   // even, in {2,4,...,16}
                ++n;
            }
    // bucket by step count: buck[k] holds blocks with steps == 2k
    static int buck[9][576];
    int bn[9] = {0};
    for (int i = 0; i < n; ++i) { int b = steps[i] >> 1; buck[b][bn[b]++] = enc[i]; }
    // counts: bn[8]=464, bn[1..7]=16 each.
    // Under round-robin dispatch, positions (c, 256+c, 512+c) share a CU.
    // Triples (64 CUs, sum 34): (16,16,2)x16 (16,14,4)x16 (16,12,6)x16 (16,10,8)x16
    // Pairs (192 CUs, sum 32): (16,16). Heavy block first in each CU slot.
    MapArg mp{};
    int a = 0;
    for (int c = 0; c < 16; ++c) {
        mp.m[c] = (unsigned short)buck[8][a++];
        mp.m[256 + c] = (unsigned short)buck[8][a++];
        mp.m[512 + c] = (unsigned short)buck[1][c];
    }
    for (int c = 16; c < 32; ++c) {
        mp.m[c] = (unsigned short)buck[8][a++];
        mp.m[256 + c] = (unsigned short)buck[7][c - 16];
        mp.m[512 + c] = (unsigned short)buck[2][c - 16];
    }
    for (int c = 32; c < 48; ++c) {
        mp.m[c] = (unsigned short)buck[8][a++];
        mp.m[256 + c] = (unsigned short)buck[6][c - 32];
        mp.m[512 + c] = (unsigned short)buck[3][c - 32];
    }
    for (int c = 48; c < 64; ++c) {
        mp.m[c] = (unsigned short)buck[8][a++];
        mp.m[256 + c] = (unsigned short)buck[5][c - 48];
        mp.m[512 + c] = (unsigned short)buck[4][c - 48];
    }
    for (int c = 64; c < 256; ++c) {
        mp.m[c] = (unsigned short)buck[8][a++];
        mp.m[256 + c] = (unsigned short)buck[8][a++];
    }
    return mp;
}

extern "C" void kernel_launch(void* const* d_in, const int* in_sizes, int n_in,
                              void* d_out, int out_size, void* d_ws, size_t ws_size,
                              hipStream_t stream) {
    (void)in_sizes; (void)n_in; (void)out_size; (void)ws_size;
    const float* x  = (const float*)d_in[0];
    const float* Wq = (const float*)d_in[1];
    const float* Wk = (const float*)d_in[2];
    const float* Wv = (const float*)d_in[3];
    const float* Wo = (const float*)d_in[4];
    const float* bo = (const float*)d_in[5];
    float* out = (float*)d_out;

    // Workspace layout (shorts). Two time-shared regions keep total at 63.59 MB
    // (below the previous session's proven 65.09 MB footprint):
    //   QAb: Q during gemm_qkv/flash, then AO during merge/gemm_out (Q dead).
    //   U:   [xb|Wqb|Wkb|Wvb] during convert/gemm_qkv, then Oh (576 slots x
    //        64 x 512 bf16 = 18874368 shorts) during flash/merge.
    unsigned short* ws  = (unsigned short*)d_ws;
    unsigned short* Wob = ws;                       // 262144
    unsigned short* QAb = ws + 262144;              // 4194304 (Q, then AO)
    unsigned short* Kb  = QAb + 4194304;            // 4194304
    unsigned short* Vtb = Kb + 4194304;             // 4194304
    unsigned short* U   = Vtb + 4194304;            // 18874368 (union region)
    unsigned short* xb  = U;
    unsigned short* Wqb = U + 4194304;
    unsigned short* Wkb = Wqb + 262144;
    unsigned short* Wvb = Wkb + 262144;
    unsigned short* Ohb = U;                        // aliases xb+W* (dead by then)
    float* Lbf = (float*)(U + 18874368);            // 576 x 64 floats

    static const MapArg mp = build_map();

    convert_bf16<<<5120, 256, 0, stream>>>(x, Wq, Wk, Wv, Wo, U, Wob);

    gemm_qkv<<<dim3(4, 64, 3), 256, 0, stream>>>(xb, Wqb, Wkb, Wvb, QAb, Kb, Vtb);

    flash_mfma<<<576, 512, 0, stream>>>(QAb, Kb, Vtb, Ohb, Lbf, mp);

    flash_merge<<<8192, 256, 0, stream>>>(Ohb, Lbf, QAb);

    gemm_out<<<dim3(4, 64), 256, 0, stream>>>(QAb, Wob, bo, out);
}

// Round 3
// 215.453 us; speedup vs baseline: 1.0816x; 1.0816x over previous
//
#include <hip/hip_runtime.h>
#include <hip/hip_bf16.h>

#define S_LEN 4096
#define E_DIM 512
#define B_DIM 2
#define M_ROWS (B_DIM * S_LEN)   // 8192

typedef __attribute__((ext_vector_type(8))) short short8;   // 8 bf16 = 4 VGPRs
typedef __attribute__((ext_vector_type(4))) float floatx4;  // MFMA C/D

__device__ __forceinline__ unsigned short f2bf(float f) {
    unsigned u = __float_as_uint(f);
    unsigned r = (u + 0x7fffu + ((u >> 16) & 1u)) >> 16;   // RNE
    return (unsigned short)r;
}
__device__ __forceinline__ float bf2f(unsigned short u) {
    return __uint_as_float((unsigned)u << 16);
}

// async 16B/lane global->LDS (lds dest = wave-uniform base + lane*16)
__device__ __forceinline__ void async_copy16(unsigned short* lds, const unsigned short* g) {
    auto gp = (const __attribute__((address_space(1))) unsigned int*)g;
    auto lp = (__attribute__((address_space(3))) unsigned int*)lds;
    __builtin_amdgcn_global_load_lds(gp, lp, 16, 0, 0);
}

// 576 live (tile,ch,bb) blocks; enc = t | ch<<6 | bb<<9
struct MapArg { unsigned short m[576]; };

// ---------------- convert fp32 inputs -> bf16 workspace ----------------
// dstU gets [x | Wq | Wk | Wv] (region later reused for Oh); Wo goes to dstWo.
__global__ __launch_bounds__(256) void convert_bf16(
    const float* __restrict__ x,  const float* __restrict__ wq,
    const float* __restrict__ wk, const float* __restrict__ wv,
    const float* __restrict__ wo, unsigned short* __restrict__ dstU,
    unsigned short* __restrict__ dstWo)
{
    long i = (long)blockIdx.x * 1024 + (long)threadIdx.x * 4;
    const float* src; long off; unsigned short* dst; long doff;
    if      (i < 4194304) { src = x;  off = i;           dst = dstU;  doff = i; }
    else if (i < 4456448) { src = wq; off = i - 4194304; dst = dstU;  doff = i; }
    else if (i < 4718592) { src = wk; off = i - 4456448; dst = dstU;  doff = i; }
    else if (i < 4980736) { src = wv; off = i - 4718592; dst = dstU;  doff = i; }
    else                  { src = wo; off = i - 4980736; dst = dstWo; doff = i - 4980736; }
    float4 v = *(const float4*)(src + off);
    ushort4 o;
    o.x = f2bf(v.x); o.y = f2bf(v.y); o.z = f2bf(v.z); o.w = f2bf(v.w);
    *(ushort4*)(dst + doff) = o;
}

// ---------------- MFMA GEMM core: C[m,n] = sum_k A[m,k]*W[n,k] ----------------
__device__ __forceinline__ void gemm_core(
    const unsigned short* __restrict__ A, const unsigned short* __restrict__ W,
    void* __restrict__ Cv, const float* __restrict__ bias, int mode,
    int m0, int n0)
{
    __shared__ unsigned short As[128 * 32];
    __shared__ unsigned short Bs[128 * 32];
    const int tid = threadIdx.x;
    const int lane = tid & 63, wave = tid >> 6;
    const int wm = wave >> 1, wn = wave & 1;
    const int q4 = lane >> 4, l16 = lane & 15;

    floatx4 acc[4][4];
#pragma unroll
    for (int i = 0; i < 4; ++i)
#pragma unroll
        for (int j = 0; j < 4; ++j) acc[i][j] = (floatx4){0.f, 0.f, 0.f, 0.f};

    const int srow = lane >> 2;
    const int scol = (lane & 3) * 8;

    for (int k0 = 0; k0 < 512; k0 += 32) {
        async_copy16(&As[(wave * 16) * 32],
                     A + (size_t)(m0 + wave * 16 + srow) * 512 + k0 + scol);
        async_copy16(&As[(64 + wave * 16) * 32],
                     A + (size_t)(m0 + 64 + wave * 16 + srow) * 512 + k0 + scol);
        async_copy16(&Bs[(wave * 16) * 32],
                     W + (size_t)(n0 + wave * 16 + srow) * 512 + k0 + scol);
        async_copy16(&Bs[(64 + wave * 16) * 32],
                     W + (size_t)(n0 + 64 + wave * 16 + srow) * 512 + k0 + scol);
        __syncthreads();
        short8 af[4], bfr[4];
#pragma unroll
        for (int i = 0; i < 4; ++i) {
            af[i]  = *(const short8*)&As[(wm * 64 + i * 16 + l16) * 32 + q4 * 8];
            bfr[i] = *(const short8*)&Bs[(wn * 64 + i * 16 + l16) * 32 + q4 * 8];
        }
#pragma unroll
        for (int i = 0; i < 4; ++i)
#pragma unroll
            for (int j = 0; j < 4; ++j)
                acc[i][j] = __builtin_amdgcn_mfma_f32_16x16x32_bf16(af[i], bfr[j], acc[i][j], 0, 0, 0);
        __syncthreads();
    }

    if (mode == 0) {
        unsigned short* C = (unsigned short*)Cv;
#pragma unroll
        for (int i = 0; i < 4; ++i) {
            int rowb = m0 + wm * 64 + i * 16 + q4 * 4;
#pragma unroll
            for (int j = 0; j < 4; ++j) {
                int col = n0 + wn * 64 + j * 16 + l16;
#pragma unroll
                for (int rg = 0; rg < 4; ++rg)
                    C[(size_t)(rowb + rg) * 512 + col] = f2bf(acc[i][j][rg]);
            }
        }
    } else if (mode == 1) {
        unsigned short* C = (unsigned short*)Cv;
#pragma unroll
        for (int i = 0; i < 4; ++i) {
            int grow = m0 + wm * 64 + i * 16 + q4 * 4;
            int b = grow >> 12, s = grow & 4095;
#pragma unroll
            for (int j = 0; j < 4; ++j) {
                int e = n0 + wn * 64 + j * 16 + l16;
                ushort4 pk;
                pk.x = f2bf(acc[i][j][0]); pk.y = f2bf(acc[i][j][1]);
                pk.z = f2bf(acc[i][j][2]); pk.w = f2bf(acc[i][j][3]);
                *(ushort4*)(C + (size_t)b * 512 * 4096 + (size_t)e * 4096 + s) = pk;
            }
        }
    } else {
        float* C = (float*)Cv;
#pragma unroll
        for (int i = 0; i < 4; ++i) {
            int rowb = m0 + wm * 64 + i * 16 + q4 * 4;
#pragma unroll
            for (int j = 0; j < 4; ++j) {
                int col = n0 + wn * 64 + j * 16 + l16;
                float bv = bias[col];
#pragma unroll
                for (int rg = 0; rg < 4; ++rg)
                    C[(size_t)(rowb + rg) * 512 + col] = acc[i][j][rg] + bv;
            }
        }
    }
}

__global__ __launch_bounds__(256) void gemm_qkv(
    const unsigned short* __restrict__ xb,
    const unsigned short* __restrict__ Wqb, const unsigned short* __restrict__ Wkb,
    const unsigned short* __restrict__ Wvb,
    unsigned short* __restrict__ Qb, unsigned short* __restrict__ Kb,
    unsigned short* __restrict__ Vtb)
{
    const int z = blockIdx.z;
    const unsigned short* W = (z == 0) ? Wqb : (z == 1) ? Wkb : Wvb;
    unsigned short* C = (z == 0) ? Qb : (z == 1) ? Kb : Vtb;
    gemm_core(xb, W, C, nullptr, (z == 2) ? 1 : 0, blockIdx.y * 128, blockIdx.x * 128);
}

__global__ __launch_bounds__(256) void gemm_out(
    const unsigned short* __restrict__ AOb, const unsigned short* __restrict__ Wob,
    const float* __restrict__ bo, float* __restrict__ out)
{
    gemm_core(AOb, Wob, out, bo, 2, blockIdx.y * 128, blockIdx.x * 128);
}

// ---------------- MFMA flash attention, Tm=64, Tn=128, 512 thr ----------------
// Anti-causal (keep j >= i). Each wave computes FULL-depth (512-dim) QK^T for
// its own 16 keys -> no cross-wave slice reduction, softmax in-register, ONE
// barrier per 128-key step. Q tile staged once per block in LDS (chunk-XOR
// swizzled: linear gload_lds dest + inverse-swizzled global source + swizzled
// ds_read). P goes to PV's A-operand via small double-buffered Plds.
__global__ __launch_bounds__(512, 2) void flash_mfma(
    const unsigned short* __restrict__ Qg, const unsigned short* __restrict__ Kg,
    const unsigned short* __restrict__ Vt,
    unsigned short* __restrict__ Oh, float* __restrict__ Lb, MapArg map)
{
    const int enc = map.m[blockIdx.x];
    const int tile = enc & 63, ch = (enc >> 6) & 7, bb = enc >> 9;
    const int i0 = tile * 64;
    const int lo0 = 512 * ch, hi = lo0 + 512;
    const int lo = (i0 > lo0) ? i0 : lo0;
    const int lo_al = lo & ~127;            // extra keys < i0 are masked to 0
    const int nsteps = (hi - lo_al) >> 7;   // 1..4

    const int tid = threadIdx.x;
    const int lane = tid & 63, w = tid >> 6;
    const int q4 = lane >> 4, l16 = lane & 15;
    const int e = l16 & 7;                  // Q-swizzle key
    const float scale = 0.044194173824159216f;  // 1/sqrt(512)
    const float MREF = 4.0f;

    __shared__ unsigned short Qs[64 * 512];       // 64 KB, chunk-swizzled
    __shared__ unsigned short Plds[2][64][136];   // 34 KB, padded stride
    __shared__ float Lred[8][64];

    const size_t rowbase = (size_t)bb * S_LEN;
    const size_t vbase   = (size_t)bb * (size_t)512 * 4096;

    // ---- stage Q tile (64 rows x 512 dims) into LDS, chunk-swizzled:
    // LDS 16B-chunk position c of row r holds global chunk (c ^ (r&7)).
#pragma unroll
    for (int rr = 0; rr < 8; ++rr) {
        const int row = w * 8 + rr;
        const unsigned short* src = Qg + (rowbase + i0 + row) * 512
                                    + ((lane ^ (row & 7)) << 3);
        async_copy16(&Qs[row * 512], src);
    }

    floatx4 oacc[4][4];   // rows (mg,q4,rg) x dims [64w + nc*16 + l16]
#pragma unroll
    for (int mg = 0; mg < 4; ++mg)
#pragma unroll
        for (int nc = 0; nc < 4; ++nc) oacc[mg][nc] = (floatx4){0.f, 0.f, 0.f, 0.f};
    float l_acc[4] = {0.f, 0.f, 0.f, 0.f};

    // per-lane swizzled Q read bases (ks even / ks odd)
    const unsigned short* qb0 = &Qs[l16 * 512 + ((q4 ^ e) << 3)];
    const unsigned short* qb1 = &Qs[l16 * 512 + (((q4 + 4) ^ e) << 3)];
    // K base: this wave's 16 keys (row = j0 + 16w + l16), dims q4*8
    const unsigned short* kpbase = Kg + (rowbase + 16 * w + l16) * 512 + (q4 << 3);

    __syncthreads();   // Qs ready (drains the global_load_lds queue)

    for (int t = 0; t < nsteps; ++t) {
        const int j0 = lo_al + t * 128;
        const int buf = t & 1;

        // K frags: 16 keys x full 512 dims for this wave
        short8 kf[16];
        const unsigned short* kp = kpbase + (size_t)j0 * 512;
#pragma unroll
        for (int ks = 0; ks < 16; ++ks)
            kf[ks] = *(const short8*)(kp + ks * 32);

        // S^T = K * Q^T full depth: sf[mg] lane(q4,l16):
        //   key = j0+16w+q4*4+rg, qrow = i0+mg*16+l16
        floatx4 sf[4];
#pragma unroll
        for (int mg = 0; mg < 4; ++mg) sf[mg] = (floatx4){0.f, 0.f, 0.f, 0.f};
        __builtin_amdgcn_s_setprio(1);
#pragma unroll
        for (int ks = 0; ks < 16; ++ks) {
            const unsigned short* qb = (ks & 1) ? qb1 : qb0;
#pragma unroll
            for (int mg = 0; mg < 4; ++mg) {
                short8 a = *(const short8*)(qb + mg * 8192 + (ks >> 1) * 64);
                sf[mg] = __builtin_amdgcn_mfma_f32_16x16x32_bf16(kf[ks], a, sf[mg], 0, 0, 0);
            }
        }
        __builtin_amdgcn_s_setprio(0);

        // issue V loads now; they land under softmax + barrier drain
        short8 vf[4][4];   // [nc dim-block][kslot]
#pragma unroll
        for (int nc = 0; nc < 4; ++nc) {
            const unsigned short* vpn = Vt + vbase
                + (size_t)(w * 64 + nc * 16 + l16) * 4096 + j0 + (q4 << 3);
#pragma unroll
            for (int kslot = 0; kslot < 4; ++kslot)
                vf[nc][kslot] = *(const short8*)(vpn + kslot * 32);
        }

        // in-register softmax (fixed reference MREF) + mask, write P to Plds
        const int kb = j0 + 16 * w + (q4 << 2);
        const bool full = (j0 >= i0 + 64);   // block-uniform
#pragma unroll
        for (int mg = 0; mg < 4; ++mg) {
            const int row = i0 + mg * 16 + l16;
            float p0 = __expf(sf[mg][0] * scale - MREF);
            float p1 = __expf(sf[mg][1] * scale - MREF);
            float p2 = __expf(sf[mg][2] * scale - MREF);
            float p3 = __expf(sf[mg][3] * scale - MREF);
            if (!full) {
                p0 = (kb + 0 >= row) ? p0 : 0.f;
                p1 = (kb + 1 >= row) ? p1 : 0.f;
                p2 = (kb + 2 >= row) ? p2 : 0.f;
                p3 = (kb + 3 >= row) ? p3 : 0.f;
            }
            l_acc[mg] += p0 + p1 + p2 + p3;
            ushort4 pk;
            pk.x = f2bf(p0); pk.y = f2bf(p1); pk.z = f2bf(p2); pk.w = f2bf(p3);
            *(ushort4*)&Plds[buf][mg * 16 + l16][16 * w + (q4 << 2)] = pk;
        }
        __syncthreads();   // Plds[buf] complete; also drains vf loads

        // PV: O[rows][64w..64w+64) += P * V
        __builtin_amdgcn_s_setprio(1);
#pragma unroll
        for (int kslot = 0; kslot < 4; ++kslot) {
#pragma unroll
            for (int mg = 0; mg < 4; ++mg) {
                short8 ap = *(const short8*)&Plds[buf][mg * 16 + l16][kslot * 32 + (q4 << 3)];
#pragma unroll
                for (int nc = 0; nc < 4; ++nc)
                    oacc[mg][nc] = __builtin_amdgcn_mfma_f32_16x16x32_bf16(
                        ap, vf[nc][kslot], oacc[mg][nc], 0, 0, 0);
            }
        }
        __builtin_amdgcn_s_setprio(0);
        // next iteration writes Plds[buf^1]: safe without a second barrier
    }

    // ---- row-sum reduction: l_acc[mg] is row (mg*16+l16) over keys (q4, w)
#pragma unroll
    for (int mg = 0; mg < 4; ++mg) {
        float v = l_acc[mg];
        v += __shfl_xor(v, 16, 64);
        v += __shfl_xor(v, 32, 64);
        if (q4 == 0) Lred[w][mg * 16 + l16] = v;
    }
    __syncthreads();

    const int slot = 8 * ch * (ch + 1) + bb * 8 * (ch + 1) + tile;
    if (tid < 64) {
        float sum = 0.f;
#pragma unroll
        for (int ww = 0; ww < 8; ++ww) sum += Lred[ww][tid];
        Lb[(size_t)slot * 64 + tid] = sum;
    }

    unsigned short* Op = Oh + (size_t)slot * 64 * 512;
#pragma unroll
    for (int mg = 0; mg < 4; ++mg)
#pragma unroll
        for (int nc = 0; nc < 4; ++nc)
#pragma unroll
            for (int rg = 0; rg < 4; ++rg)
                Op[(size_t)(mg * 16 + q4 * 4 + rg) * 512 + w * 64 + nc * 16 + l16]
                    = f2bf(oacc[mg][nc][rg]);
}

// O = (sum_ch Ohat_ch) / (sum_ch l_ch) over valid chunks ch >= i>>9
__global__ __launch_bounds__(256) void flash_merge(
    const unsigned short* __restrict__ Oh, const float* __restrict__ Lb,
    unsigned short* __restrict__ AO)
{
    const int row = blockIdx.x;            // 0..8191
    const int c = threadIdx.x * 2;
    const int bb = row >> 12, i = row & 4095;
    const int t = i >> 6, ri = i & 63;
    const int chmin = i >> 9;
    float lsum = 0.f, v0 = 0.f, v1 = 0.f;
    for (int ch = chmin; ch < 8; ++ch) {
        int slot = 8 * ch * (ch + 1) + bb * 8 * (ch + 1) + t;
        lsum += Lb[(size_t)slot * 64 + ri];
        const unsigned short* p = Oh + (size_t)slot * 64 * 512 + (size_t)ri * 512 + c;
        v0 += bf2f(p[0]);
        v1 += bf2f(p[1]);
    }
    float inv = 1.f / lsum;
    ushort2 o; o.x = f2bf(v0 * inv); o.y = f2bf(v1 * inv);
    *(ushort2*)(AO + (size_t)row * 512 + c) = o;
}

static MapArg build_map() {
    // enumerate 576 live blocks with step counts (128-key steps)
    int enc[576], steps[576], n = 0;
    for (int bb = 0; bb < 2; ++bb)
        for (int ch = 0; ch < 8; ++ch)
            for (int t = 0; t < 8 * (ch + 1); ++t) {
                int i0 = t * 64, lo0 = 512 * ch, hi = lo0 + 512;
                int lo = (i0 > lo0) ? i0 : lo0;
                int lo_al = lo & ~127;
                enc[n] = t | (ch << 6) | (bb << 9);
                steps[n] = (hi - lo_al) >> 7;   // 1..4
                ++n;
            }
    // heavy-first order: with dynamic dispatch, light blocks fill the tail
    MapArg mp{};
    int idx = 0;
    for (int sv = 4; sv >= 1; --sv)
        for (int i = 0; i < n; ++i)
            if (steps[i] == sv) mp.m[idx++] = (unsigned short)enc[i];
    return mp;
}

extern "C" void kernel_launch(void* const* d_in, const int* in_sizes, int n_in,
                              void* d_out, int out_size, void* d_ws, size_t ws_size,
                              hipStream_t stream) {
    (void)in_sizes; (void)n_in; (void)out_size; (void)ws_size;
    const float* x  = (const float*)d_in[0];
    const float* Wq = (const float*)d_in[1];
    const float* Wk = (const float*)d_in[2];
    const float* Wv = (const float*)d_in[3];
    const float* Wo = (const float*)d_in[4];
    const float* bo = (const float*)d_in[5];
    float* out = (float*)d_out;

    // Workspace layout (shorts). Two time-shared regions keep total at 63.59 MB
    // (same proven footprint as the passing Round-2 kernel):
    //   QAb: Q during gemm_qkv/flash, then AO during merge/gemm_out (Q dead).
    //   U:   [xb|Wqb|Wkb|Wvb] during convert/gemm_qkv, then Oh (576 slots x
    //        64 x 512 bf16 = 18874368 shorts) during flash/merge.
    unsigned short* ws  = (unsigned short*)d_ws;
    unsigned short* Wob = ws;                       // 262144
    unsigned short* QAb = ws + 262144;              // 4194304 (Q, then AO)
    unsigned short* Kb  = QAb + 4194304;            // 4194304
    unsigned short* Vtb = Kb + 4194304;             // 4194304
    unsigned short* U   = Vtb + 4194304;            // 18874368 (union region)
    unsigned short* xb  = U;
    unsigned short* Wqb = U + 4194304;
    unsigned short* Wkb = Wqb + 262144;
    unsigned short* Wvb = Wkb + 262144;
    unsigned short* Ohb = U;                        // aliases xb+W* (dead by then)
    float* Lbf = (float*)(U + 18874368);            // 576 x 64 floats

    static const MapArg mp = build_map();

    convert_bf16<<<5120, 256, 0, stream>>>(x, Wq, Wk, Wv, Wo, U, Wob);

    gemm_qkv<<<dim3(4, 64, 3), 256, 0, stream>>>(xb, Wqb, Wkb, Wvb, QAb, Kb, Vtb);

    flash_mfma<<<576, 512, 0, stream>>>(QAb, Kb, Vtb, Ohb, Lbf, mp);

    flash_merge<<<8192, 256, 0, stream>>>(Ohb, Lbf, QAb);

    gemm_out<<<dim3(4, 64), 256, 0, stream>>>(QAb, Wob, bo, out);
}